// Round 6
// baseline (673.377 us; speedup 1.0000x reference)
//
#include <hip/hip_runtime.h>
#include <math.h>

#define FW 50
#define FH 38
#define NPIX 1900   // 38*50
#define NROIS 512

// padded layouts
#define CSH 2470    // horizontal-consumed: [c][y*65 + x + t], width 65 = 50+15
#define CSV 2650    // vertical-consumed:   [c][x*53 + y + t], height 53 = 38+15

typedef __bf16 bf16x8 __attribute__((ext_vector_type(8)));
typedef float  f32x4  __attribute__((ext_vector_type(4)));

__device__ __forceinline__ unsigned short f2b(float f) {
    unsigned int u = __float_as_uint(f);
    unsigned int r = (u + 0x7fffu + ((u >> 16) & 1u)) >> 16;   // RNE
    return (unsigned short)r;
}

// ---------------- prep kernels ----------------

__global__ __launch_bounds__(256) void zero_us(unsigned short* __restrict__ p, int n) {
    int i = (blockIdx.x * 256 + threadIdx.x) * 8;
    if (i < n) { uint4 z; z.x = z.y = z.z = z.w = 0u; *(uint4*)(p + i) = z; }
}

__global__ __launch_bounds__(256) void cvt_bf16(
    const float* __restrict__ in, unsigned short* __restrict__ out, int n)
{
    int i = (blockIdx.x * 256 + threadIdx.x) * 4;
    if (i >= n) return;
    float4 v = *(const float4*)(in + i);
    ushort2 a, b;
    a.x = f2b(v.x); a.y = f2b(v.y);
    b.x = f2b(v.z); b.y = f2b(v.w);
    *(ushort2*)(out + i)     = a;
    *(ushort2*)(out + i + 2) = b;
}

__global__ __launch_bounds__(256) void cvt_pad(
    const float* __restrict__ in, unsigned short* __restrict__ out,
    int rows, int Kin, int Kout)
{
    int idx = blockIdx.x * 256 + threadIdx.x;
    if (idx >= rows * Kout) return;
    int rw = idx / Kout, k = idx - rw * Kout;
    out[idx] = (k < Kin) ? f2b(in[(size_t)rw * Kin + k]) : (unsigned short)0;
}

// weights fp32 [M][Kc][15] -> bf16 [M][Kc*16] (tap 15 = 0)
__global__ __launch_bounds__(256) void repack_w(
    const float* __restrict__ w, unsigned short* __restrict__ out, int n)
{
    int idx = blockIdx.x * 256 + threadIdx.x;
    if (idx >= n) return;
    int t = idx & 15;
    int oc = idx >> 4;
    out[idx] = (t < 15) ? f2b(w[oc * 15 + t]) : (unsigned short)0;
}

// x fp32 [c][y][x] -> bf16 padded horizontal [c][y*65 + xc], xc = x+7
__global__ __launch_bounds__(256) void xpad_h(
    const float* __restrict__ xs, unsigned short* __restrict__ out)
{
    int idx = blockIdx.x * 256 + threadIdx.x;
    if (idx >= 2048 * CSH) return;
    int c = idx / CSH;
    int rem = idx - c * CSH;
    int y = rem / 65;
    int xc = rem - y * 65 - 7;
    unsigned short v = 0;
    if (xc >= 0 && xc < FW) v = f2b(xs[(c * FH + y) * FW + xc]);
    out[idx] = v;
}

// x fp32 [c][y][x] -> bf16 padded vertical (x-major) [c][x*53 + yc], yc = y+7
__global__ __launch_bounds__(256) void xpad_v(
    const float* __restrict__ xs, unsigned short* __restrict__ out)
{
    int idx = blockIdx.x * 256 + threadIdx.x;
    if (idx >= 2048 * CSV) return;
    int c = idx / CSV;
    int rem = idx - c * CSV;
    int xx = rem / 53;
    int yc = rem - xx * 53 - 7;
    unsigned short v = 0;
    if (yc >= 0 && yc < FH) v = f2b(xs[(c * FH + yc) * FW + xx]);
    out[idx] = v;
}

// ---------------------------------------------------------------------------
// Tap-padded bf16 MFMA conv-as-GEMM, v3:
//  - A (weights) fragments loaded DIRECTLY from global (k-contiguous 16B per
//    lane, L1/L2-resident after XCD swizzle) -- no LDS round-trip for A.
//  - B double-buffered in LDS -> ONE barrier per K-step.
//  - Register prefetch of next K-step's A frags + B dwords.
// Block 64(M) x 64(pix), 4 waves 2x2, wave 32x32, BK=32.
// XCD swizzle: id%8 == z%8 keeps one weight slice per XCD L2.
// OOB A-rows (M=490 case) clamp to M-1; garbage lands in P's Mpad padding.
// ---------------------------------------------------------------------------
__global__ __launch_bounds__(256) void conv_tap(
    const unsigned short* __restrict__ Wt,   // [M][Kp] bf16 (tap-16 packed)
    const unsigned short* __restrict__ Xp,   // [Kc][CS] padded bf16
    float* __restrict__ P,
    int M, int Kp, int Mpad, int CS, int yMul, int xMul,
    int zShift, int nsplit)
{
    const int id = blockIdx.x;
    const int w  = id & 63;
    const int xt = id >> 6;
    const int yt = w >> zShift;
    const int zt = w & (nsplit - 1);

    const int Ks = Kp / nsplit;
    const int k0 = zt * Ks;
    const int tid  = threadIdx.x;
    const int lane = tid & 63;
    const int wave = tid >> 6;
    const int mbase = yt * 64;
    const int pbase = xt * 64;

    __shared__ unsigned short Bt[2][64][40];

    // B staging: 64 pixels x 32 k; thread: pixel=tid>>2, quarter=(tid&3) -> 8 ks
    const int b_pix = tid >> 2;
    const int q     = tid & 3;
    int p = pbase + b_pix;
    if (p > NPIX - 1) p = NPIX - 1;          // clamp (stores guarded)
    const int py = p / FW, px = p - py * FW;
    const int pixBase = py * yMul + px * xMul;
    const int eoff = pixBase + ((q & 1) << 3);
    const unsigned* __restrict__ Bdw = (const unsigned*)Xp;

    f32x4 acc[2][2];
#pragma unroll
    for (int i = 0; i < 2; ++i)
#pragma unroll
        for (int j = 0; j < 2; ++j)
#pragma unroll
            for (int r = 0; r < 4; ++r) acc[i][j][r] = 0.f;

    const int wy = (wave >> 1) * 32;
    const int wx = (wave & 1) * 32;
    const int lm = lane & 15;
    const int l8 = (lane >> 4) * 8;

    // A fragment pointers (per-lane, k-contiguous 16B)
    const int r0 = min(mbase + wy + lm, M - 1);
    const int r1 = min(mbase + wy + 16 + lm, M - 1);
    const unsigned short* A0 = Wt + (size_t)r0 * Kp + l8;
    const unsigned short* A1 = Wt + (size_t)r1 * Kp + l8;

    unsigned d[5];
    auto loadB = [&](int kt) {
        const int cg = (kt >> 4) + (q >> 1);           // channel for this quarter
        const unsigned base = ((unsigned)(cg * CS + eoff)) >> 1;
#pragma unroll
        for (int j = 0; j < 5; ++j) d[j] = Bdw[base + j];
    };

    uint4 aCur0 = *(const uint4*)(A0 + k0);
    uint4 aCur1 = *(const uint4*)(A1 + k0);
    loadB(k0);
    const unsigned sh = ((unsigned)(pixBase & 1)) << 4;  // CS even -> parity fixed

    int buf = 0;
    for (int kt = k0; kt < k0 + Ks; kt += 32) {
        unsigned ob[4];
#pragma unroll
        for (int j = 0; j < 4; ++j)
            ob[j] = __builtin_amdgcn_alignbit(d[j + 1], d[j], sh);
        *(uint4*)&Bt[buf][b_pix][q << 3] = *(uint4*)&ob[0];
        __syncthreads();

        const bool more = (kt + 32 < k0 + Ks);
        uint4 aN0, aN1;
        if (more) {
            aN0 = *(const uint4*)(A0 + kt + 32);
            aN1 = *(const uint4*)(A1 + kt + 32);
            loadB(kt + 32);
        }

        bf16x8 af0 = __builtin_bit_cast(bf16x8, aCur0);
        bf16x8 af1 = __builtin_bit_cast(bf16x8, aCur1);
        bf16x8 bf0 = __builtin_bit_cast(bf16x8, *(const uint4*)&Bt[buf][wx + lm][l8]);
        bf16x8 bf1 = __builtin_bit_cast(bf16x8, *(const uint4*)&Bt[buf][wx + 16 + lm][l8]);

        acc[0][0] = __builtin_amdgcn_mfma_f32_16x16x32_bf16(af0, bf0, acc[0][0], 0, 0, 0);
        acc[0][1] = __builtin_amdgcn_mfma_f32_16x16x32_bf16(af0, bf1, acc[0][1], 0, 0, 0);
        acc[1][0] = __builtin_amdgcn_mfma_f32_16x16x32_bf16(af1, bf0, acc[1][0], 0, 0, 0);
        acc[1][1] = __builtin_amdgcn_mfma_f32_16x16x32_bf16(af1, bf1, acc[1][1], 0, 0, 0);

        if (more) { aCur0 = aN0; aCur1 = aN1; }
        buf ^= 1;
    }

    float* Pp = P + (size_t)zt * Mpad * NPIX;
#pragma unroll
    for (int i = 0; i < 2; ++i) {
        const int m0 = mbase + wy + i * 16 + (lane >> 4) * 4;
#pragma unroll
        for (int j = 0; j < 2; ++j) {
            const int pp = pbase + wx + j * 16 + lm;
            if (pp < NPIX) {
#pragma unroll
                for (int r = 0; r < 4; ++r)
                    Pp[(size_t)(m0 + r) * NPIX + pp] = acc[i][j][r];
            }
        }
    }
}

// conv1 reduce: sum partials + bias -> bf16 into next conv's padded layout
__global__ void reduce_pad(
    const float* __restrict__ P, int Mpad, int nsplit,
    const float* __restrict__ bias, int M,
    unsigned short* __restrict__ outb, int CS, int yMul, int xMul)
{
    int idx = blockIdx.x * 256 + threadIdx.x;
    if (idx >= M * NPIX) return;
    int o = idx / NPIX;
    int p = idx - o * NPIX;
    float s = bias[o];
    for (int sp = 0; sp < nsplit; ++sp)
        s += P[((size_t)sp * Mpad + o) * NPIX + p];
    int y = p / FW, x = p - y * FW;
    outb[(size_t)o * CS + y * yMul + x * xMul + 7] = f2b(s);
}

// conv2 reduce: sum partials + bias (+add, relu) -> fp32 raster
__global__ void reduce_bias(
    const float* __restrict__ P, int Mpad, int nsplit,
    const float* __restrict__ bias, int M,
    const float* __restrict__ addbuf, int relu,
    float* __restrict__ outf)
{
    int idx = blockIdx.x * blockDim.x + threadIdx.x;
    if (idx >= M * NPIX) return;
    int o = idx / NPIX;
    int p = idx - o * NPIX;
    float s = bias[o];
    for (int sp = 0; sp < nsplit; ++sp)
        s += P[((size_t)sp * Mpad + o) * NPIX + p];
    if (addbuf) s += addbuf[idx];
    if (relu) s = fmaxf(s, 0.f);
    outf[idx] = s;
}

// ---------------------------------------------------------------------------
// PSROI bilinear pooling (fp32 h) -> bf16 pooled [512][512] zero-padded
// ---------------------------------------------------------------------------
__global__ __launch_bounds__(512) void pool_kernel(
    const float* __restrict__ h, const float* __restrict__ rois,
    unsigned short* __restrict__ pooledb)
{
    int n = blockIdx.x;
    int k = threadIdx.x;
    if (k >= 490) {
        pooledb[(size_t)n * 512 + k] = 0;
        return;
    }
    float x1 = rois[n * 4 + 0], y1 = rois[n * 4 + 1];
    float x2 = rois[n * 4 + 2], y2 = rois[n * 4 + 3];
    float xmin = x1 * (1.f / 16.f) / 50.f;
    float ymin = y1 * (1.f / 16.f) / 38.f;
    float xmax = x2 * (1.f / 16.f) / 50.f;
    float ymax = y2 * (1.f / 16.f) / 38.f;
    float step_x = (xmax - xmin) / 7.f;
    float step_y = (ymax - ymin) / 7.f;
    int bin = k / 10;
    int bi = bin / 7, bj = bin - bi * 7;
    const float* ch = h + (size_t)k * NPIX;
    float m = -INFINITY;
#pragma unroll
    for (int sy = 0; sy < 2; ++sy) {
        float yv = (ymin + (float)(bi + sy) * step_y) * 37.f;
        float y0 = floorf(yv);
        float fy = yv - y0;
        int yi0 = min(max((int)y0, 0), 37);
        int yi1 = min(max((int)y0 + 1, 0), 37);
#pragma unroll
        for (int sx = 0; sx < 2; ++sx) {
            float xv = (xmin + (float)(bj + sx) * step_x) * 49.f;
            float x0 = floorf(xv);
            float fx = xv - x0;
            int xi0 = min(max((int)x0, 0), 49);
            int xi1 = min(max((int)x0 + 1, 0), 49);
            float v00 = ch[yi0 * FW + xi0], v01 = ch[yi0 * FW + xi1];
            float v10 = ch[yi1 * FW + xi0], v11 = ch[yi1 * FW + xi1];
            float top = v00 + (v01 - v00) * fx;
            float bot = v10 + (v11 - v10) * fx;
            float val = top + (bot - top) * fy;
            m = fmaxf(m, val);
        }
    }
    pooledb[(size_t)n * 512 + k] = f2b(m);
}

// ---------------------------------------------------------------------------
// bf16 MFMA NT GEMM (FC): A = weights [M][Kld], B = acts [512][Kld], split-K.
// ---------------------------------------------------------------------------
__global__ __launch_bounds__(256) void fc_mfma(
    const unsigned short* __restrict__ Wb,
    const unsigned short* __restrict__ Act,
    float* __restrict__ P, int M, int Kld, int Mpad)
{
    const int Ks = Kld / gridDim.z;
    const int k0 = blockIdx.z * Ks;
    const int tid  = threadIdx.x;
    const int lane = tid & 63;
    const int wave = tid >> 6;
    const int mbase = blockIdx.x * 64;
    const int nbase = blockIdx.y * 64;

    __shared__ unsigned short As[64][40];
    __shared__ unsigned short Bs[64][40];

    const int s_r  = tid >> 2;
    const int s_k8 = (tid & 3) << 3;
    const int a_row = mbase + s_r;
    const bool a_ok = a_row < M;
    const unsigned short* Abase = Wb + (size_t)a_row * Kld + s_k8;
    const unsigned short* Bbase = Act + (size_t)(nbase + s_r) * Kld + s_k8;

    f32x4 acc[2][2];
#pragma unroll
    for (int i = 0; i < 2; ++i)
#pragma unroll
        for (int j = 0; j < 2; ++j)
#pragma unroll
            for (int r = 0; r < 4; ++r) acc[i][j][r] = 0.f;

    const int mh = (wave >> 1) * 32;
    const int nh = (wave & 1) * 32;
    const int lm = lane & 15;
    const int l8 = (lane >> 4) * 8;

    uint4 aReg, bReg;
    if (a_ok) aReg = *(const uint4*)(Abase + k0);
    else { aReg.x = aReg.y = aReg.z = aReg.w = 0u; }
    bReg = *(const uint4*)(Bbase + k0);

    for (int kt = k0; kt < k0 + Ks; kt += 32) {
        *(uint4*)&As[s_r][s_k8] = aReg;
        *(uint4*)&Bs[s_r][s_k8] = bReg;
        __syncthreads();

        if (kt + 32 < k0 + Ks) {
            if (a_ok) aReg = *(const uint4*)(Abase + kt + 32);
            bReg = *(const uint4*)(Bbase + kt + 32);
        }

        bf16x8 a0 = __builtin_bit_cast(bf16x8, *(const uint4*)&As[mh + lm][l8]);
        bf16x8 a1 = __builtin_bit_cast(bf16x8, *(const uint4*)&As[mh + 16 + lm][l8]);
        bf16x8 b0 = __builtin_bit_cast(bf16x8, *(const uint4*)&Bs[nh + lm][l8]);
        bf16x8 b1 = __builtin_bit_cast(bf16x8, *(const uint4*)&Bs[nh + 16 + lm][l8]);

        acc[0][0] = __builtin_amdgcn_mfma_f32_16x16x32_bf16(a0, b0, acc[0][0], 0, 0, 0);
        acc[0][1] = __builtin_amdgcn_mfma_f32_16x16x32_bf16(a0, b1, acc[0][1], 0, 0, 0);
        acc[1][0] = __builtin_amdgcn_mfma_f32_16x16x32_bf16(a1, b0, acc[1][0], 0, 0, 0);
        acc[1][1] = __builtin_amdgcn_mfma_f32_16x16x32_bf16(a1, b1, acc[1][1], 0, 0, 0);
        __syncthreads();
    }

#pragma unroll
    for (int ms = 0; ms < 2; ++ms)
#pragma unroll
        for (int ns = 0; ns < 2; ++ns) {
            int n  = nbase + nh + ns * 16 + lm;
            int m0 = mbase + mh + ms * 16 + (lane >> 4) * 4;
            float* Pp = P + ((size_t)blockIdx.z * NROIS + n) * Mpad + m0;
            *(f32x4*)Pp = acc[ms][ns];
        }
}

__global__ void fc_reduce(
    const float* __restrict__ P, int Mpad, int M, int nsplit,
    const float* __restrict__ bias, int relu,
    float* __restrict__ outf, unsigned short* __restrict__ outb)
{
    int idx = blockIdx.x * 256 + threadIdx.x;
    if (idx >= NROIS * M) return;
    int n = idx / M, m = idx - n * M;
    float s = bias[m];
    for (int sp = 0; sp < nsplit; ++sp)
        s += P[((size_t)sp * NROIS + n) * Mpad + m];
    if (relu) s = fmaxf(s, 0.f);
    if (outf) outf[idx] = s;
    if (outb) outb[idx] = f2b(s);
}

extern "C" void kernel_launch(void* const* d_in, const int* in_sizes, int n_in,
                              void* d_out, int out_size, void* d_ws, size_t ws_size,
                              hipStream_t stream) {
    const float* x         = (const float*)d_in[0];
    const float* rois      = (const float*)d_in[1];
    const float* w_col_max = (const float*)d_in[2];
    const float* b_col_max = (const float*)d_in[3];
    const float* w_col     = (const float*)d_in[4];
    const float* b_col     = (const float*)d_in[5];
    const float* w_row_max = (const float*)d_in[6];
    const float* b_row_max = (const float*)d_in[7];
    const float* w_row     = (const float*)d_in[8];
    const float* b_row     = (const float*)d_in[9];
    const float* w_fc1     = (const float*)d_in[10];
    const float* b_fc1     = (const float*)d_in[11];
    const float* w_score   = (const float*)d_in[12];
    const float* b_score   = (const float*)d_in[13];
    const float* w_loc     = (const float*)d_in[14];
    const float* b_loc     = (const float*)d_in[15];

    float* part = (float*)d_ws;                        // 7,782,400 f = 31.1MB
    unsigned short* XvU   = (unsigned short*)(part + 7782400); // 5,427,264
    unsigned short* XhU   = XvU + 5427264;             // 5,058,624
    unsigned short* wbig  = XhU + 5058624;             // 8,388,608 (col-max, then row-max)
    unsigned short* wc16  = wbig + 8388608;            // 2,007,040
    unsigned short* wr16  = wc16 + 2007040;            // 2,007,040
    unsigned short* c1colb= wr16 + 2007040;            //   632,384
    unsigned short* c1rowb= c1colb + 632384;           //   678,464
    unsigned short* wfc1b = c1rowb + 678464;           // 1,048,576
    unsigned short* pooledb = wfc1b + 1048576;         //   262,144
    unsigned short* fc1b  = pooledb + 262144;          // 1,048,576
    unsigned short* wlocb = fc1b + 1048576;            //   663,552
    unsigned short* wscoreb = wlocb + 663552;          //   165,888
    float* hcol = (float*)XvU;                         // alias (Xv dead by then)
    float* h    = (float*)XhU;                         // alias (Xh dead by then)
    // total ~86 MB

    // ---- prep ----
    xpad_v<<<21200, 256, 0, stream>>>(x, XvU);
    xpad_h<<<19760, 256, 0, stream>>>(x, XhU);
    zero_us<<<309, 256, 0, stream>>>(c1colb, 632384);
    zero_us<<<332, 256, 0, stream>>>(c1rowb, 678464);
    repack_w<<<32768, 256, 0, stream>>>(w_col_max, wbig, 8388608);
    repack_w<<<7840, 256, 0, stream>>>(w_col, wc16, 2007040);
    repack_w<<<7840, 256, 0, stream>>>(w_row, wr16, 2007040);
    cvt_pad <<<4096, 256, 0, stream>>>(w_fc1, wfc1b, 2048, 490, 512);
    cvt_bf16<<<648,  256, 0, stream>>>(w_loc, wlocb, 663552);
    cvt_bf16<<<162,  256, 0, stream>>>(w_score, wscoreb, 165888);

    // ---- conv1 col (vertical 15x1), M=256: 30x * 4y * 16z = 1920 blocks ----
    conv_tap<<<1920, 256, 0, stream>>>(wbig, XvU, part, 256, 32768, 256, CSV, 1, 53, 4, 16);
    reduce_pad<<<1900, 256, 0, stream>>>(part, 256, 16, b_col_max, 256, c1colb, CSH, 65, 1);
    repack_w<<<32768, 256, 0, stream>>>(w_row_max, wbig, 8388608);
    // ---- conv1 row (horizontal 1x15) ----
    conv_tap<<<1920, 256, 0, stream>>>(wbig, XhU, part, 256, 32768, 256, CSH, 65, 1, 4, 16);
    reduce_pad<<<1900, 256, 0, stream>>>(part, 256, 16, b_row_max, 256, c1rowb, CSV, 1, 53);

    // ---- conv2 col (horizontal 1x15), M=490 (Mpad 512): 30x * 8y * 8z ----
    conv_tap<<<1920, 256, 0, stream>>>(wc16, c1colb, part, 490, 4096, 512, CSH, 65, 1, 3, 8);
    reduce_bias<<<3637, 256, 0, stream>>>(part, 512, 8, b_col, 490, nullptr, 0, hcol);
    // ---- conv2 row (vertical 15x1); h = relu(hcol + this) ----
    conv_tap<<<1920, 256, 0, stream>>>(wr16, c1rowb, part, 490, 4096, 512, CSV, 1, 53, 3, 8);
    reduce_bias<<<3637, 256, 0, stream>>>(part, 512, 8, b_row, 490, hcol, 1, h);

    // ---- PSROI pooling ----
    pool_kernel<<<512, 512, 0, stream>>>(h, rois, pooledb);

    float* out = (float*)d_out;
    // fc1: M=2048, K=512, split 2, relu -> bf16
    fc_mfma<<<dim3(32, 8, 2), 256, 0, stream>>>(wfc1b, pooledb, part, 2048, 512, 2048);
    fc_reduce<<<4096, 256, 0, stream>>>(part, 2048, 2048, 2, b_fc1, 1, nullptr, fc1b);
    // roi_cls_locs: M=324, K=2048, split 4
    fc_mfma<<<dim3(6, 8, 4), 256, 0, stream>>>(wlocb, fc1b, part, 324, 2048, 384);
    fc_reduce<<<648, 256, 0, stream>>>(part, 384, 324, 4, b_loc, 0, out, nullptr);
    // roi_scores: M=81, K=2048, split 8
    fc_mfma<<<dim3(2, 8, 8), 256, 0, stream>>>(wscoreb, fc1b, part, 81, 2048, 128);
    fc_reduce<<<162, 256, 0, stream>>>(part, 128, 81, 8, b_score, 0, out + 512 * 324, nullptr);
}

// Round 7
// 465.045 us; speedup vs baseline: 1.4480x; 1.4480x over previous
//
#include <hip/hip_runtime.h>
#include <math.h>

#define FW 50
#define FH 38
#define NPIX 1900   // 38*50
#define NROIS 512

// padded layouts
#define CSH 2470    // horizontal-consumed: [c][y*65 + x + t], width 65 = 50+15
#define CSV 2650    // vertical-consumed:   [c][x*53 + y + t], height 53 = 38+15

typedef __bf16 bf16x8 __attribute__((ext_vector_type(8)));
typedef float  f32x4  __attribute__((ext_vector_type(4)));

__device__ __forceinline__ unsigned short f2b(float f) {
    unsigned int u = __float_as_uint(f);
    unsigned int r = (u + 0x7fffu + ((u >> 16) & 1u)) >> 16;   // RNE
    return (unsigned short)r;
}

// ---------------- prep kernels ----------------

__global__ __launch_bounds__(256) void zero_us(unsigned short* __restrict__ p, int n) {
    int i = (blockIdx.x * 256 + threadIdx.x) * 8;
    if (i < n) { uint4 z; z.x = z.y = z.z = z.w = 0u; *(uint4*)(p + i) = z; }
}

__global__ __launch_bounds__(256) void cvt_bf16(
    const float* __restrict__ in, unsigned short* __restrict__ out, int n)
{
    int i = (blockIdx.x * 256 + threadIdx.x) * 4;
    if (i >= n) return;
    float4 v = *(const float4*)(in + i);
    ushort2 a, b;
    a.x = f2b(v.x); a.y = f2b(v.y);
    b.x = f2b(v.z); b.y = f2b(v.w);
    *(ushort2*)(out + i)     = a;
    *(ushort2*)(out + i + 2) = b;
}

__global__ __launch_bounds__(256) void cvt_pad(
    const float* __restrict__ in, unsigned short* __restrict__ out,
    int rows, int Kin, int Kout)
{
    int idx = blockIdx.x * 256 + threadIdx.x;
    if (idx >= rows * Kout) return;
    int rw = idx / Kout, k = idx - rw * Kout;
    out[idx] = (k < Kin) ? f2b(in[(size_t)rw * Kin + k]) : (unsigned short)0;
}

// weights fp32 [M][Kc][15] -> bf16 [M][Kc*16] (tap 15 = 0)
__global__ __launch_bounds__(256) void repack_w(
    const float* __restrict__ w, unsigned short* __restrict__ out, int n)
{
    int idx = blockIdx.x * 256 + threadIdx.x;
    if (idx >= n) return;
    int t = idx & 15;
    int oc = idx >> 4;
    out[idx] = (t < 15) ? f2b(w[oc * 15 + t]) : (unsigned short)0;
}

// x fp32 [c][y][x] -> bf16 padded horizontal [c][y*65 + xc], xc = x+7
__global__ __launch_bounds__(256) void xpad_h(
    const float* __restrict__ xs, unsigned short* __restrict__ out)
{
    int idx = blockIdx.x * 256 + threadIdx.x;
    if (idx >= 2048 * CSH) return;
    int c = idx / CSH;
    int rem = idx - c * CSH;
    int y = rem / 65;
    int xc = rem - y * 65 - 7;
    unsigned short v = 0;
    if (xc >= 0 && xc < FW) v = f2b(xs[(c * FH + y) * FW + xc]);
    out[idx] = v;
}

// x fp32 [c][y][x] -> bf16 padded vertical (x-major) [c][x*53 + yc], yc = y+7
__global__ __launch_bounds__(256) void xpad_v(
    const float* __restrict__ xs, unsigned short* __restrict__ out)
{
    int idx = blockIdx.x * 256 + threadIdx.x;
    if (idx >= 2048 * CSV) return;
    int c = idx / CSV;
    int rem = idx - c * CSV;
    int xx = rem / 53;
    int yc = rem - xx * 53 - 7;
    unsigned short v = 0;
    if (yc >= 0 && yc < FH) v = f2b(xs[(c * FH + yc) * FW + xx]);
    out[idx] = v;
}

// ---------------------------------------------------------------------------
// Tap-padded bf16 MFMA conv-as-GEMM, v4 (R5 structure, bigger M-tile):
// Block tile 128(M) x 64(pix), 4 waves 2x2, wave tile 64x32, BK=32.
// Coalesced LDS staging (uint4/thread) + register prefetch + 2 barriers.
// XCD swizzle: id%8 == zt%8 keeps one weight slice per XCD L2.
//   zt = id & zMask; yt = (id>>zBits) & yMask; xt = id >> xShift
// ---------------------------------------------------------------------------
__global__ __launch_bounds__(256) void conv_tap(
    const unsigned short* __restrict__ Wt,   // [M][Kp] bf16 (tap-16 packed)
    const unsigned short* __restrict__ Xp,   // [Kc][CS] padded bf16
    float* __restrict__ P,
    int M, int Kp, int Mpad, int CS, int yMul, int xMul,
    int zMask, int zBits, int yMask, int xShift)
{
    const int id = blockIdx.x;
    const int zt = id & zMask;
    const int yt = (id >> zBits) & yMask;
    const int xt = id >> xShift;
    const int nsplit = zMask + 1;

    const int Ks = Kp / nsplit;
    const int k0 = zt * Ks;
    const int tid  = threadIdx.x;
    const int lane = tid & 63;
    const int wave = tid >> 6;
    const int mbase = yt * 128;
    const int pbase = xt * 64;

    __shared__ unsigned short As[128][40];
    __shared__ unsigned short Bt[64][40];

    // A staging: 128 rows x 32 k; thread: row=tid>>1, k-half=(tid&1)*16 -> 2 uint4
    const int a_row = tid >> 1;
    const int a_k16 = (tid & 1) << 4;
    const int a_src = min(mbase + a_row, M - 1);   // clamp; dup rows land in Mpad pad
    const unsigned short* Abase = Wt + (size_t)a_src * Kp + a_k16;

    // B staging: 64 pixels x 32 k; thread: pixel=tid>>2, quarter=(tid&3) -> 8 ks
    const int b_pix = tid >> 2;
    const int q     = tid & 3;
    int p = pbase + b_pix;
    if (p > NPIX - 1) p = NPIX - 1;          // clamp (stores guarded)
    const int py = p / FW, px = p - py * FW;
    const int pixBase = py * yMul + px * xMul;
    const int eoff = pixBase + ((q & 1) << 3);
    const unsigned* __restrict__ Bdw = (const unsigned*)Xp;

    f32x4 acc[4][2];
#pragma unroll
    for (int i = 0; i < 4; ++i)
#pragma unroll
        for (int j = 0; j < 2; ++j)
#pragma unroll
            for (int r = 0; r < 4; ++r) acc[i][j][r] = 0.f;

    const int wy = (wave >> 1) * 64;
    const int wx = (wave & 1) * 32;
    const int lm = lane & 15;
    const int l8 = (lane >> 4) * 8;

    uint4 aR0, aR1;
    unsigned d[5];

    auto loadA = [&](int kt) {
        aR0 = *(const uint4*)(Abase + kt);
        aR1 = *(const uint4*)(Abase + kt + 8);
    };
    auto loadB = [&](int kt) {
        const int cg = (kt >> 4) + (q >> 1);           // channel for this quarter
        const unsigned base = ((unsigned)(cg * CS + eoff)) >> 1;
#pragma unroll
        for (int j = 0; j < 5; ++j) d[j] = Bdw[base + j];
    };

    loadA(k0); loadB(k0);
    const unsigned sh = ((unsigned)(pixBase & 1)) << 4;  // CS even -> parity fixed

    for (int kt = k0; kt < k0 + Ks; kt += 32) {
        unsigned ob[4];
#pragma unroll
        for (int j = 0; j < 4; ++j)
            ob[j] = __builtin_amdgcn_alignbit(d[j + 1], d[j], sh);
        *(uint4*)&As[a_row][a_k16]     = aR0;
        *(uint4*)&As[a_row][a_k16 + 8] = aR1;
        *(uint4*)&Bt[b_pix][q << 3] = *(uint4*)&ob[0];
        __syncthreads();

        if (kt + 32 < k0 + Ks) { loadA(kt + 32); loadB(kt + 32); }

        bf16x8 af[4], bfr[2];
#pragma unroll
        for (int i = 0; i < 4; ++i)
            af[i]  = __builtin_bit_cast(bf16x8, *(const uint4*)&As[wy + i * 16 + lm][l8]);
#pragma unroll
        for (int j = 0; j < 2; ++j)
            bfr[j] = __builtin_bit_cast(bf16x8, *(const uint4*)&Bt[wx + j * 16 + lm][l8]);

#pragma unroll
        for (int i = 0; i < 4; ++i)
#pragma unroll
            for (int j = 0; j < 2; ++j)
                acc[i][j] = __builtin_amdgcn_mfma_f32_16x16x32_bf16(af[i], bfr[j], acc[i][j], 0, 0, 0);
        __syncthreads();
    }

    float* Pp = P + (size_t)zt * Mpad * NPIX;
#pragma unroll
    for (int i = 0; i < 4; ++i) {
        const int m0 = mbase + wy + i * 16 + (lane >> 4) * 4;
#pragma unroll
        for (int j = 0; j < 2; ++j) {
            const int pp = pbase + wx + j * 16 + lm;
            if (pp < NPIX) {
#pragma unroll
                for (int r = 0; r < 4; ++r)
                    Pp[(size_t)(m0 + r) * NPIX + pp] = acc[i][j][r];
            }
        }
    }
}

// conv1 reduce: sum partials + bias -> bf16 into next conv's padded layout
__global__ void reduce_pad(
    const float* __restrict__ P, int Mpad, int nsplit,
    const float* __restrict__ bias, int M,
    unsigned short* __restrict__ outb, int CS, int yMul, int xMul)
{
    int idx = blockIdx.x * 256 + threadIdx.x;
    if (idx >= M * NPIX) return;
    int o = idx / NPIX;
    int p = idx - o * NPIX;
    float s = bias[o];
    for (int sp = 0; sp < nsplit; ++sp)
        s += P[((size_t)sp * Mpad + o) * NPIX + p];
    int y = p / FW, x = p - y * FW;
    outb[(size_t)o * CS + y * yMul + x * xMul + 7] = f2b(s);
}

// conv2 reduce: sum partials + bias (+add, relu) -> fp32 raster
__global__ void reduce_bias(
    const float* __restrict__ P, int Mpad, int nsplit,
    const float* __restrict__ bias, int M,
    const float* __restrict__ addbuf, int relu,
    float* __restrict__ outf)
{
    int idx = blockIdx.x * blockDim.x + threadIdx.x;
    if (idx >= M * NPIX) return;
    int o = idx / NPIX;
    int p = idx - o * NPIX;
    float s = bias[o];
    for (int sp = 0; sp < nsplit; ++sp)
        s += P[((size_t)sp * Mpad + o) * NPIX + p];
    if (addbuf) s += addbuf[idx];
    if (relu) s = fmaxf(s, 0.f);
    outf[idx] = s;
}

// ---------------------------------------------------------------------------
// PSROI bilinear pooling (fp32 h) -> bf16 pooled [512][512] zero-padded
// ---------------------------------------------------------------------------
__global__ __launch_bounds__(512) void pool_kernel(
    const float* __restrict__ h, const float* __restrict__ rois,
    unsigned short* __restrict__ pooledb)
{
    int n = blockIdx.x;
    int k = threadIdx.x;
    if (k >= 490) {
        pooledb[(size_t)n * 512 + k] = 0;
        return;
    }
    float x1 = rois[n * 4 + 0], y1 = rois[n * 4 + 1];
    float x2 = rois[n * 4 + 2], y2 = rois[n * 4 + 3];
    float xmin = x1 * (1.f / 16.f) / 50.f;
    float ymin = y1 * (1.f / 16.f) / 38.f;
    float xmax = x2 * (1.f / 16.f) / 50.f;
    float ymax = y2 * (1.f / 16.f) / 38.f;
    float step_x = (xmax - xmin) / 7.f;
    float step_y = (ymax - ymin) / 7.f;
    int bin = k / 10;
    int bi = bin / 7, bj = bin - bi * 7;
    const float* ch = h + (size_t)k * NPIX;
    float m = -INFINITY;
#pragma unroll
    for (int sy = 0; sy < 2; ++sy) {
        float yv = (ymin + (float)(bi + sy) * step_y) * 37.f;
        float y0 = floorf(yv);
        float fy = yv - y0;
        int yi0 = min(max((int)y0, 0), 37);
        int yi1 = min(max((int)y0 + 1, 0), 37);
#pragma unroll
        for (int sx = 0; sx < 2; ++sx) {
            float xv = (xmin + (float)(bj + sx) * step_x) * 49.f;
            float x0 = floorf(xv);
            float fx = xv - x0;
            int xi0 = min(max((int)x0, 0), 49);
            int xi1 = min(max((int)x0 + 1, 0), 49);
            float v00 = ch[yi0 * FW + xi0], v01 = ch[yi0 * FW + xi1];
            float v10 = ch[yi1 * FW + xi0], v11 = ch[yi1 * FW + xi1];
            float top = v00 + (v01 - v00) * fx;
            float bot = v10 + (v11 - v10) * fx;
            float val = top + (bot - top) * fy;
            m = fmaxf(m, val);
        }
    }
    pooledb[(size_t)n * 512 + k] = f2b(m);
}

// ---------------------------------------------------------------------------
// bf16 MFMA NT GEMM (FC): A = weights [M][Kld], B = acts [512][Kld], split-K.
// ---------------------------------------------------------------------------
__global__ __launch_bounds__(256) void fc_mfma(
    const unsigned short* __restrict__ Wb,
    const unsigned short* __restrict__ Act,
    float* __restrict__ P, int M, int Kld, int Mpad)
{
    const int Ks = Kld / gridDim.z;
    const int k0 = blockIdx.z * Ks;
    const int tid  = threadIdx.x;
    const int lane = tid & 63;
    const int wave = tid >> 6;
    const int mbase = blockIdx.x * 64;
    const int nbase = blockIdx.y * 64;

    __shared__ unsigned short As[64][40];
    __shared__ unsigned short Bs[64][40];

    const int s_r  = tid >> 2;
    const int s_k8 = (tid & 3) << 3;
    const int a_row = mbase + s_r;
    const bool a_ok = a_row < M;
    const unsigned short* Abase = Wb + (size_t)a_row * Kld + s_k8;
    const unsigned short* Bbase = Act + (size_t)(nbase + s_r) * Kld + s_k8;

    f32x4 acc[2][2];
#pragma unroll
    for (int i = 0; i < 2; ++i)
#pragma unroll
        for (int j = 0; j < 2; ++j)
#pragma unroll
            for (int r = 0; r < 4; ++r) acc[i][j][r] = 0.f;

    const int mh = (wave >> 1) * 32;
    const int nh = (wave & 1) * 32;
    const int lm = lane & 15;
    const int l8 = (lane >> 4) * 8;

    uint4 aReg, bReg;
    if (a_ok) aReg = *(const uint4*)(Abase + k0);
    else { aReg.x = aReg.y = aReg.z = aReg.w = 0u; }
    bReg = *(const uint4*)(Bbase + k0);

    for (int kt = k0; kt < k0 + Ks; kt += 32) {
        *(uint4*)&As[s_r][s_k8] = aReg;
        *(uint4*)&Bs[s_r][s_k8] = bReg;
        __syncthreads();

        if (kt + 32 < k0 + Ks) {
            if (a_ok) aReg = *(const uint4*)(Abase + kt + 32);
            bReg = *(const uint4*)(Bbase + kt + 32);
        }

        bf16x8 a0 = __builtin_bit_cast(bf16x8, *(const uint4*)&As[mh + lm][l8]);
        bf16x8 a1 = __builtin_bit_cast(bf16x8, *(const uint4*)&As[mh + 16 + lm][l8]);
        bf16x8 b0 = __builtin_bit_cast(bf16x8, *(const uint4*)&Bs[nh + lm][l8]);
        bf16x8 b1 = __builtin_bit_cast(bf16x8, *(const uint4*)&Bs[nh + 16 + lm][l8]);

        acc[0][0] = __builtin_amdgcn_mfma_f32_16x16x32_bf16(a0, b0, acc[0][0], 0, 0, 0);
        acc[0][1] = __builtin_amdgcn_mfma_f32_16x16x32_bf16(a0, b1, acc[0][1], 0, 0, 0);
        acc[1][0] = __builtin_amdgcn_mfma_f32_16x16x32_bf16(a1, b0, acc[1][0], 0, 0, 0);
        acc[1][1] = __builtin_amdgcn_mfma_f32_16x16x32_bf16(a1, b1, acc[1][1], 0, 0, 0);
        __syncthreads();
    }

#pragma unroll
    for (int ms = 0; ms < 2; ++ms)
#pragma unroll
        for (int ns = 0; ns < 2; ++ns) {
            int n  = nbase + nh + ns * 16 + lm;
            int m0 = mbase + mh + ms * 16 + (lane >> 4) * 4;
            float* Pp = P + ((size_t)blockIdx.z * NROIS + n) * Mpad + m0;
            *(f32x4*)Pp = acc[ms][ns];
        }
}

__global__ void fc_reduce(
    const float* __restrict__ P, int Mpad, int M, int nsplit,
    const float* __restrict__ bias, int relu,
    float* __restrict__ outf, unsigned short* __restrict__ outb)
{
    int idx = blockIdx.x * 256 + threadIdx.x;
    if (idx >= NROIS * M) return;
    int n = idx / M, m = idx - n * M;
    float s = bias[m];
    for (int sp = 0; sp < nsplit; ++sp)
        s += P[((size_t)sp * NROIS + n) * Mpad + m];
    if (relu) s = fmaxf(s, 0.f);
    if (outf) outf[idx] = s;
    if (outb) outb[idx] = f2b(s);
}

extern "C" void kernel_launch(void* const* d_in, const int* in_sizes, int n_in,
                              void* d_out, int out_size, void* d_ws, size_t ws_size,
                              hipStream_t stream) {
    const float* x         = (const float*)d_in[0];
    const float* rois      = (const float*)d_in[1];
    const float* w_col_max = (const float*)d_in[2];
    const float* b_col_max = (const float*)d_in[3];
    const float* w_col     = (const float*)d_in[4];
    const float* b_col     = (const float*)d_in[5];
    const float* w_row_max = (const float*)d_in[6];
    const float* b_row_max = (const float*)d_in[7];
    const float* w_row     = (const float*)d_in[8];
    const float* b_row     = (const float*)d_in[9];
    const float* w_fc1     = (const float*)d_in[10];
    const float* b_fc1     = (const float*)d_in[11];
    const float* w_score   = (const float*)d_in[12];
    const float* b_score   = (const float*)d_in[13];
    const float* w_loc     = (const float*)d_in[14];
    const float* b_loc     = (const float*)d_in[15];

    float* part = (float*)d_ws;                        // 7,782,400 f = 31.1MB
    unsigned short* XvU   = (unsigned short*)(part + 7782400); // 5,427,264
    unsigned short* XhU   = XvU + 5427264;             // 5,058,624
    unsigned short* wbig  = XhU + 5058624;             // 8,388,608 (col-max, then row-max)
    unsigned short* wc16  = wbig + 8388608;            // 2,007,040
    unsigned short* wr16  = wc16 + 2007040;            // 2,007,040
    unsigned short* c1colb= wr16 + 2007040;            //   632,384
    unsigned short* c1rowb= c1colb + 632384;           //   678,464
    unsigned short* wfc1b = c1rowb + 678464;           // 1,048,576
    unsigned short* pooledb = wfc1b + 1048576;         //   262,144
    unsigned short* fc1b  = pooledb + 262144;          // 1,048,576
    unsigned short* wlocb = fc1b + 1048576;            //   663,552
    unsigned short* wscoreb = wlocb + 663552;          //   165,888
    float* hcol = (float*)XvU;                         // alias (Xv dead by then)
    float* h    = (float*)XhU;                         // alias (Xh dead by then)
    // total ~86 MB

    // ---- prep ----
    xpad_v<<<21200, 256, 0, stream>>>(x, XvU);
    xpad_h<<<19760, 256, 0, stream>>>(x, XhU);
    zero_us<<<309, 256, 0, stream>>>(c1colb, 632384);
    zero_us<<<332, 256, 0, stream>>>(c1rowb, 678464);
    repack_w<<<32768, 256, 0, stream>>>(w_col_max, wbig, 8388608);
    repack_w<<<7840, 256, 0, stream>>>(w_col, wc16, 2007040);
    repack_w<<<7840, 256, 0, stream>>>(w_row, wr16, 2007040);
    cvt_pad <<<4096, 256, 0, stream>>>(w_fc1, wfc1b, 2048, 490, 512);
    cvt_bf16<<<648,  256, 0, stream>>>(w_loc, wlocb, 663552);
    cvt_bf16<<<162,  256, 0, stream>>>(w_score, wscoreb, 165888);

    // ---- conv1 col (vertical 15x1), M=256: 30x * 2y(128) * 16z = 960 blocks
    conv_tap<<<960, 256, 0, stream>>>(wbig, XvU, part, 256, 32768, 256, CSV, 1, 53, 15, 4, 1, 5);
    reduce_pad<<<1900, 256, 0, stream>>>(part, 256, 16, b_col_max, 256, c1colb, CSH, 65, 1);
    repack_w<<<32768, 256, 0, stream>>>(w_row_max, wbig, 8388608);
    // ---- conv1 row (horizontal 1x15) ----
    conv_tap<<<960, 256, 0, stream>>>(wbig, XhU, part, 256, 32768, 256, CSH, 65, 1, 15, 4, 1, 5);
    reduce_pad<<<1900, 256, 0, stream>>>(part, 256, 16, b_row_max, 256, c1rowb, CSV, 1, 53);

    // ---- conv2 col (horizontal 1x15), M=490 (Mpad 512): 30x * 4y(128) * 8z
    conv_tap<<<960, 256, 0, stream>>>(wc16, c1colb, part, 490, 4096, 512, CSH, 65, 1, 7, 3, 3, 5);
    reduce_bias<<<3637, 256, 0, stream>>>(part, 512, 8, b_col, 490, nullptr, 0, hcol);
    // ---- conv2 row (vertical 15x1); h = relu(hcol + this) ----
    conv_tap<<<960, 256, 0, stream>>>(wr16, c1rowb, part, 490, 4096, 512, CSV, 1, 53, 7, 3, 3, 5);
    reduce_bias<<<3637, 256, 0, stream>>>(part, 512, 8, b_row, 490, hcol, 1, h);

    // ---- PSROI pooling ----
    pool_kernel<<<512, 512, 0, stream>>>(h, rois, pooledb);

    float* out = (float*)d_out;
    // fc1: M=2048, K=512, split 2, relu -> bf16
    fc_mfma<<<dim3(32, 8, 2), 256, 0, stream>>>(wfc1b, pooledb, part, 2048, 512, 2048);
    fc_reduce<<<4096, 256, 0, stream>>>(part, 2048, 2048, 2, b_fc1, 1, nullptr, fc1b);
    // roi_cls_locs: M=324, K=2048, split 4
    fc_mfma<<<dim3(6, 8, 4), 256, 0, stream>>>(wlocb, fc1b, part, 324, 2048, 384);
    fc_reduce<<<648, 256, 0, stream>>>(part, 384, 324, 4, b_loc, 0, out, nullptr);
    // roi_scores: M=81, K=2048, split 8
    fc_mfma<<<dim3(2, 8, 8), 256, 0, stream>>>(wscoreb, fc1b, part, 81, 2048, 128);
    fc_reduce<<<162, 256, 0, stream>>>(part, 128, 81, 8, b_score, 0, out + 512 * 324, nullptr);
}

// Round 8
// 423.024 us; speedup vs baseline: 1.5918x; 1.0993x over previous
//
#include <hip/hip_runtime.h>
#include <math.h>

#define FW 50
#define FH 38
#define NPIX 1900   // 38*50
#define NROIS 512

// padded layouts
#define CSH 2470    // horizontal-consumed: [c][y*65 + x + t], width 65 = 50+15
#define CSV 2650    // vertical-consumed:   [c][x*53 + y + t], height 53 = 38+15

typedef __bf16 bf16x8 __attribute__((ext_vector_type(8)));
typedef float  f32x4  __attribute__((ext_vector_type(4)));
typedef float  f32x16 __attribute__((ext_vector_type(16)));

__device__ __forceinline__ unsigned short f2b(float f) {
    unsigned int u = __float_as_uint(f);
    unsigned int r = (u + 0x7fffu + ((u >> 16) & 1u)) >> 16;   // RNE
    return (unsigned short)r;
}

// ---------------- prep kernels ----------------

__global__ __launch_bounds__(256) void zero_us(unsigned short* __restrict__ p, int n) {
    int i = (blockIdx.x * 256 + threadIdx.x) * 8;
    if (i < n) { uint4 z; z.x = z.y = z.z = z.w = 0u; *(uint4*)(p + i) = z; }
}

__global__ __launch_bounds__(256) void cvt_bf16(
    const float* __restrict__ in, unsigned short* __restrict__ out, int n)
{
    int i = (blockIdx.x * 256 + threadIdx.x) * 4;
    if (i >= n) return;
    float4 v = *(const float4*)(in + i);
    ushort2 a, b;
    a.x = f2b(v.x); a.y = f2b(v.y);
    b.x = f2b(v.z); b.y = f2b(v.w);
    *(ushort2*)(out + i)     = a;
    *(ushort2*)(out + i + 2) = b;
}

__global__ __launch_bounds__(256) void cvt_pad(
    const float* __restrict__ in, unsigned short* __restrict__ out,
    int rows, int Kin, int Kout)
{
    int idx = blockIdx.x * 256 + threadIdx.x;
    if (idx >= rows * Kout) return;
    int rw = idx / Kout, k = idx - rw * Kout;
    out[idx] = (k < Kin) ? f2b(in[(size_t)rw * Kin + k]) : (unsigned short)0;
}

// weights fp32 [M][Kc][15] -> bf16 [M][Kc*16] (tap 15 = 0)
__global__ __launch_bounds__(256) void repack_w(
    const float* __restrict__ w, unsigned short* __restrict__ out, int n)
{
    int idx = blockIdx.x * 256 + threadIdx.x;
    if (idx >= n) return;
    int t = idx & 15;
    int oc = idx >> 4;
    out[idx] = (t < 15) ? f2b(w[oc * 15 + t]) : (unsigned short)0;
}

// x fp32 [c][y][x] -> bf16 padded horizontal [c][y*65 + xc], xc = x+7
__global__ __launch_bounds__(256) void xpad_h(
    const float* __restrict__ xs, unsigned short* __restrict__ out)
{
    int idx = blockIdx.x * 256 + threadIdx.x;
    if (idx >= 2048 * CSH) return;
    int c = idx / CSH;
    int rem = idx - c * CSH;
    int y = rem / 65;
    int xc = rem - y * 65 - 7;
    unsigned short v = 0;
    if (xc >= 0 && xc < FW) v = f2b(xs[(c * FH + y) * FW + xc]);
    out[idx] = v;
}

// x fp32 [c][y][x] -> bf16 padded vertical (x-major) [c][x*53 + yc], yc = y+7
__global__ __launch_bounds__(256) void xpad_v(
    const float* __restrict__ xs, unsigned short* __restrict__ out)
{
    int idx = blockIdx.x * 256 + threadIdx.x;
    if (idx >= 2048 * CSV) return;
    int c = idx / CSV;
    int rem = idx - c * CSV;
    int xx = rem / 53;
    int yc = rem - xx * 53 - 7;
    unsigned short v = 0;
    if (yc >= 0 && yc < FH) v = f2b(xs[(c * FH + yc) * FW + xx]);
    out[idx] = v;
}

// ---------------------------------------------------------------------------
// Tap-padded bf16 conv-as-GEMM, v5: 32x32x16 MFMA, wave tile 64x64.
// Block tile 128(M) x 128(pix), 4 waves 2x2, BK=32 (2 channels x 16 taps).
// Double-buffered LDS (both tiles) -> ONE barrier per K-step.
// B staging: thread = (pixel, channel-half); 16 contiguous taps via 9 dwords
// + alignbit. XCD swizzle id%8==zt%8 keeps a weight slice per XCD L2.
// C/D layout (32x32): col=lane&31, row=(reg&3)+8*(reg>>2)+4*(lane>>5).
// ---------------------------------------------------------------------------
__global__ __launch_bounds__(256) void conv_tap(
    const unsigned short* __restrict__ Wt,   // [M][Kp] bf16 (tap-16 packed)
    const unsigned short* __restrict__ Xp,   // [Kc][CS] padded bf16
    float* __restrict__ P,
    int M, int Kp, int Mpad, int CS, int yMul, int xMul,
    int zMask, int zBits, int yMask, int xShift)
{
    const int id = blockIdx.x;
    const int zt = id & zMask;
    const int yt = (id >> zBits) & yMask;
    const int xt = id >> xShift;
    const int nsplit = zMask + 1;

    const int Ks = Kp / nsplit;
    const int k0 = zt * Ks;
    const int tid  = threadIdx.x;
    const int lane = tid & 63;
    const int wave = tid >> 6;
    const int mbase = yt * 128;
    const int pbase = xt * 128;

    __shared__ unsigned short As[2][128][40];
    __shared__ unsigned short Bt[2][128][40];

    // A staging: 128 rows x 32 k; thread: row=tid>>1, k-half=(tid&1)*16
    const int a_row = tid >> 1;
    const int a_k16 = (tid & 1) << 4;
    const int a_src = min(mbase + a_row, M - 1);   // clamp; dups land in Mpad pad
    const unsigned short* Abase = Wt + (size_t)a_src * Kp + a_k16;

    // B staging: 128 pixels x 32 k; thread: pixel=tid>>1, channel-half=tid&1
    const int b_pix = tid >> 1;
    const int bh    = tid & 1;
    int p = pbase + b_pix;
    if (p > NPIX - 1) p = NPIX - 1;          // clamp (stores guarded)
    const int py = p / FW, px = p - py * FW;
    const int pixBase = py * yMul + px * xMul;
    const unsigned* __restrict__ Bdw = (const unsigned*)Xp;

    f32x16 acc[2][2];
#pragma unroll
    for (int i = 0; i < 2; ++i)
#pragma unroll
        for (int j = 0; j < 2; ++j)
#pragma unroll
            for (int r = 0; r < 16; ++r) acc[i][j][r] = 0.f;

    const int wy = (wave >> 1) * 64;
    const int wx = (wave & 1) * 64;
    const int l5 = lane & 31;
    const int l8 = (lane >> 5) * 8;

    uint4 aR0, aR1;
    unsigned d[9];

    auto loadA = [&](int kt) {
        aR0 = *(const uint4*)(Abase + kt);
        aR1 = *(const uint4*)(Abase + kt + 8);
    };
    auto loadB = [&](int kt) {
        const int cg = (kt >> 4) + bh;               // this thread's channel
        const unsigned base = ((unsigned)(cg * CS + pixBase)) >> 1;
#pragma unroll
        for (int j = 0; j < 9; ++j) d[j] = Bdw[base + j];
    };

    loadA(k0); loadB(k0);
    const unsigned sh = ((unsigned)(pixBase & 1)) << 4;  // CS even -> parity fixed

    int buf = 0;
    for (int kt = k0; kt < k0 + Ks; kt += 32) {
        unsigned ob[8];
#pragma unroll
        for (int j = 0; j < 8; ++j)
            ob[j] = __builtin_amdgcn_alignbit(d[j + 1], d[j], sh);
        *(uint4*)&As[buf][a_row][a_k16]     = aR0;
        *(uint4*)&As[buf][a_row][a_k16 + 8] = aR1;
        *(uint4*)&Bt[buf][b_pix][bh * 16]     = *(uint4*)&ob[0];
        *(uint4*)&Bt[buf][b_pix][bh * 16 + 8] = *(uint4*)&ob[4];
        __syncthreads();

        if (kt + 32 < k0 + Ks) { loadA(kt + 32); loadB(kt + 32); }

        bf16x8 af[2][2], bfr[2][2];
#pragma unroll
        for (int i = 0; i < 2; ++i)
#pragma unroll
            for (int kk = 0; kk < 2; ++kk) {
                af[i][kk]  = __builtin_bit_cast(bf16x8,
                    *(const uint4*)&As[buf][wy + i * 32 + l5][kk * 16 + l8]);
                bfr[i][kk] = __builtin_bit_cast(bf16x8,
                    *(const uint4*)&Bt[buf][wx + i * 32 + l5][kk * 16 + l8]);
            }
#pragma unroll
        for (int kk = 0; kk < 2; ++kk)
#pragma unroll
            for (int i = 0; i < 2; ++i)
#pragma unroll
                for (int j = 0; j < 2; ++j)
                    acc[i][j] = __builtin_amdgcn_mfma_f32_32x32x16_bf16(
                        af[i][kk], bfr[j][kk], acc[i][j], 0, 0, 0);
        buf ^= 1;
    }

    float* Pp = P + (size_t)zt * Mpad * NPIX;
#pragma unroll
    for (int i = 0; i < 2; ++i) {
        const int mb = mbase + wy + i * 32 + (lane >> 5) * 4;
#pragma unroll
        for (int j = 0; j < 2; ++j) {
            const int pp = pbase + wx + j * 32 + l5;
            if (pp < NPIX) {
#pragma unroll
                for (int r = 0; r < 16; ++r) {
                    const int m = mb + (r & 3) + 8 * (r >> 2);
                    Pp[(size_t)m * NPIX + pp] = acc[i][j][r];
                }
            }
        }
    }
}

// conv1 reduce: sum partials + bias -> bf16 into next conv's padded layout
__global__ void reduce_pad(
    const float* __restrict__ P, int Mpad, int nsplit,
    const float* __restrict__ bias, int M,
    unsigned short* __restrict__ outb, int CS, int yMul, int xMul)
{
    int idx = blockIdx.x * 256 + threadIdx.x;
    if (idx >= M * NPIX) return;
    int o = idx / NPIX;
    int p = idx - o * NPIX;
    float s = bias[o];
    for (int sp = 0; sp < nsplit; ++sp)
        s += P[((size_t)sp * Mpad + o) * NPIX + p];
    int y = p / FW, x = p - y * FW;
    outb[(size_t)o * CS + y * yMul + x * xMul + 7] = f2b(s);
}

// conv2 reduce: sum partials + bias (+add, relu) -> fp32 raster
__global__ void reduce_bias(
    const float* __restrict__ P, int Mpad, int nsplit,
    const float* __restrict__ bias, int M,
    const float* __restrict__ addbuf, int relu,
    float* __restrict__ outf)
{
    int idx = blockIdx.x * blockDim.x + threadIdx.x;
    if (idx >= M * NPIX) return;
    int o = idx / NPIX;
    int p = idx - o * NPIX;
    float s = bias[o];
    for (int sp = 0; sp < nsplit; ++sp)
        s += P[((size_t)sp * Mpad + o) * NPIX + p];
    if (addbuf) s += addbuf[idx];
    if (relu) s = fmaxf(s, 0.f);
    outf[idx] = s;
}

// ---------------------------------------------------------------------------
// PSROI bilinear pooling (fp32 h) -> bf16 pooled [512][512] zero-padded
// ---------------------------------------------------------------------------
__global__ __launch_bounds__(512) void pool_kernel(
    const float* __restrict__ h, const float* __restrict__ rois,
    unsigned short* __restrict__ pooledb)
{
    int n = blockIdx.x;
    int k = threadIdx.x;
    if (k >= 490) {
        pooledb[(size_t)n * 512 + k] = 0;
        return;
    }
    float x1 = rois[n * 4 + 0], y1 = rois[n * 4 + 1];
    float x2 = rois[n * 4 + 2], y2 = rois[n * 4 + 3];
    float xmin = x1 * (1.f / 16.f) / 50.f;
    float ymin = y1 * (1.f / 16.f) / 38.f;
    float xmax = x2 * (1.f / 16.f) / 50.f;
    float ymax = y2 * (1.f / 16.f) / 38.f;
    float step_x = (xmax - xmin) / 7.f;
    float step_y = (ymax - ymin) / 7.f;
    int bin = k / 10;
    int bi = bin / 7, bj = bin - bi * 7;
    const float* ch = h + (size_t)k * NPIX;
    float m = -INFINITY;
#pragma unroll
    for (int sy = 0; sy < 2; ++sy) {
        float yv = (ymin + (float)(bi + sy) * step_y) * 37.f;
        float y0 = floorf(yv);
        float fy = yv - y0;
        int yi0 = min(max((int)y0, 0), 37);
        int yi1 = min(max((int)y0 + 1, 0), 37);
#pragma unroll
        for (int sx = 0; sx < 2; ++sx) {
            float xv = (xmin + (float)(bj + sx) * step_x) * 49.f;
            float x0 = floorf(xv);
            float fx = xv - x0;
            int xi0 = min(max((int)x0, 0), 49);
            int xi1 = min(max((int)x0 + 1, 0), 49);
            float v00 = ch[yi0 * FW + xi0], v01 = ch[yi0 * FW + xi1];
            float v10 = ch[yi1 * FW + xi0], v11 = ch[yi1 * FW + xi1];
            float top = v00 + (v01 - v00) * fx;
            float bot = v10 + (v11 - v10) * fx;
            float val = top + (bot - top) * fy;
            m = fmaxf(m, val);
        }
    }
    pooledb[(size_t)n * 512 + k] = f2b(m);
}

// ---------------------------------------------------------------------------
// bf16 MFMA NT GEMM (FC): A = weights [M][Kld], B = acts [512][Kld], split-K.
// ---------------------------------------------------------------------------
__global__ __launch_bounds__(256) void fc_mfma(
    const unsigned short* __restrict__ Wb,
    const unsigned short* __restrict__ Act,
    float* __restrict__ P, int M, int Kld, int Mpad)
{
    const int Ks = Kld / gridDim.z;
    const int k0 = blockIdx.z * Ks;
    const int tid  = threadIdx.x;
    const int lane = tid & 63;
    const int wave = tid >> 6;
    const int mbase = blockIdx.x * 64;
    const int nbase = blockIdx.y * 64;

    __shared__ unsigned short As[64][40];
    __shared__ unsigned short Bs[64][40];

    const int s_r  = tid >> 2;
    const int s_k8 = (tid & 3) << 3;
    const int a_row = mbase + s_r;
    const bool a_ok = a_row < M;
    const unsigned short* Abase = Wb + (size_t)a_row * Kld + s_k8;
    const unsigned short* Bbase = Act + (size_t)(nbase + s_r) * Kld + s_k8;

    f32x4 acc[2][2];
#pragma unroll
    for (int i = 0; i < 2; ++i)
#pragma unroll
        for (int j = 0; j < 2; ++j)
#pragma unroll
            for (int r = 0; r < 4; ++r) acc[i][j][r] = 0.f;

    const int mh = (wave >> 1) * 32;
    const int nh = (wave & 1) * 32;
    const int lm = lane & 15;
    const int l8 = (lane >> 4) * 8;

    uint4 aReg, bReg;
    if (a_ok) aReg = *(const uint4*)(Abase + k0);
    else { aReg.x = aReg.y = aReg.z = aReg.w = 0u; }
    bReg = *(const uint4*)(Bbase + k0);

    for (int kt = k0; kt < k0 + Ks; kt += 32) {
        *(uint4*)&As[s_r][s_k8] = aReg;
        *(uint4*)&Bs[s_r][s_k8] = bReg;
        __syncthreads();

        if (kt + 32 < k0 + Ks) {
            if (a_ok) aReg = *(const uint4*)(Abase + kt + 32);
            bReg = *(const uint4*)(Bbase + kt + 32);
        }

        bf16x8 a0 = __builtin_bit_cast(bf16x8, *(const uint4*)&As[mh + lm][l8]);
        bf16x8 a1 = __builtin_bit_cast(bf16x8, *(const uint4*)&As[mh + 16 + lm][l8]);
        bf16x8 b0 = __builtin_bit_cast(bf16x8, *(const uint4*)&Bs[nh + lm][l8]);
        bf16x8 b1 = __builtin_bit_cast(bf16x8, *(const uint4*)&Bs[nh + 16 + lm][l8]);

        acc[0][0] = __builtin_amdgcn_mfma_f32_16x16x32_bf16(a0, b0, acc[0][0], 0, 0, 0);
        acc[0][1] = __builtin_amdgcn_mfma_f32_16x16x32_bf16(a0, b1, acc[0][1], 0, 0, 0);
        acc[1][0] = __builtin_amdgcn_mfma_f32_16x16x32_bf16(a1, b0, acc[1][0], 0, 0, 0);
        acc[1][1] = __builtin_amdgcn_mfma_f32_16x16x32_bf16(a1, b1, acc[1][1], 0, 0, 0);
        __syncthreads();
    }

#pragma unroll
    for (int ms = 0; ms < 2; ++ms)
#pragma unroll
        for (int ns = 0; ns < 2; ++ns) {
            int n  = nbase + nh + ns * 16 + lm;
            int m0 = mbase + mh + ms * 16 + (lane >> 4) * 4;
            float* Pp = P + ((size_t)blockIdx.z * NROIS + n) * Mpad + m0;
            *(f32x4*)Pp = acc[ms][ns];
        }
}

__global__ void fc_reduce(
    const float* __restrict__ P, int Mpad, int M, int nsplit,
    const float* __restrict__ bias, int relu,
    float* __restrict__ outf, unsigned short* __restrict__ outb)
{
    int idx = blockIdx.x * 256 + threadIdx.x;
    if (idx >= NROIS * M) return;
    int n = idx / M, m = idx - n * M;
    float s = bias[m];
    for (int sp = 0; sp < nsplit; ++sp)
        s += P[((size_t)sp * NROIS + n) * Mpad + m];
    if (relu) s = fmaxf(s, 0.f);
    if (outf) outf[idx] = s;
    if (outb) outb[idx] = f2b(s);
}

extern "C" void kernel_launch(void* const* d_in, const int* in_sizes, int n_in,
                              void* d_out, int out_size, void* d_ws, size_t ws_size,
                              hipStream_t stream) {
    const float* x         = (const float*)d_in[0];
    const float* rois      = (const float*)d_in[1];
    const float* w_col_max = (const float*)d_in[2];
    const float* b_col_max = (const float*)d_in[3];
    const float* w_col     = (const float*)d_in[4];
    const float* b_col     = (const float*)d_in[5];
    const float* w_row_max = (const float*)d_in[6];
    const float* b_row_max = (const float*)d_in[7];
    const float* w_row     = (const float*)d_in[8];
    const float* b_row     = (const float*)d_in[9];
    const float* w_fc1     = (const float*)d_in[10];
    const float* b_fc1     = (const float*)d_in[11];
    const float* w_score   = (const float*)d_in[12];
    const float* b_score   = (const float*)d_in[13];
    const float* w_loc     = (const float*)d_in[14];
    const float* b_loc     = (const float*)d_in[15];

    float* part = (float*)d_ws;                        // 7,782,400 f = 31.1MB
    unsigned short* XvU   = (unsigned short*)(part + 7782400); // 5,427,264
    unsigned short* XhU   = XvU + 5427264;             // 5,058,624
    unsigned short* wbig  = XhU + 5058624;             // 8,388,608 (col-max, then row-max)
    unsigned short* wc16  = wbig + 8388608;            // 2,007,040
    unsigned short* wr16  = wc16 + 2007040;            // 2,007,040
    unsigned short* c1colb= wr16 + 2007040;            //   632,384
    unsigned short* c1rowb= c1colb + 632384;           //   678,464
    unsigned short* wfc1b = c1rowb + 678464;           // 1,048,576
    unsigned short* pooledb = wfc1b + 1048576;         //   262,144
    unsigned short* fc1b  = pooledb + 262144;          // 1,048,576
    unsigned short* wlocb = fc1b + 1048576;            //   663,552
    unsigned short* wscoreb = wlocb + 663552;          //   165,888
    float* hcol = (float*)XvU;                         // alias (Xv dead by then)
    float* h    = (float*)XhU;                         // alias (Xh dead by then)
    // total ~86 MB

    // ---- prep ----
    xpad_v<<<21200, 256, 0, stream>>>(x, XvU);
    xpad_h<<<19760, 256, 0, stream>>>(x, XhU);
    zero_us<<<641, 256, 0, stream>>>(c1colb, 1310848);   // c1colb + c1rowb (contiguous)
    repack_w<<<32768, 256, 0, stream>>>(w_col_max, wbig, 8388608);
    repack_w<<<7840, 256, 0, stream>>>(w_col, wc16, 2007040);
    repack_w<<<7840, 256, 0, stream>>>(w_row, wr16, 2007040);
    cvt_pad <<<4096, 256, 0, stream>>>(w_fc1, wfc1b, 2048, 490, 512);
    cvt_bf16<<<648,  256, 0, stream>>>(w_loc, wlocb, 663552);
    cvt_bf16<<<162,  256, 0, stream>>>(w_score, wscoreb, 165888);

    // ---- conv1 col (vertical 15x1), M=256: 15x(128) * 2y(128) * 16z = 480
    conv_tap<<<480, 256, 0, stream>>>(wbig, XvU, part, 256, 32768, 256, CSV, 1, 53, 15, 4, 1, 5);
    reduce_pad<<<1900, 256, 0, stream>>>(part, 256, 16, b_col_max, 256, c1colb, CSH, 65, 1);
    repack_w<<<32768, 256, 0, stream>>>(w_row_max, wbig, 8388608);
    // ---- conv1 row (horizontal 1x15) ----
    conv_tap<<<480, 256, 0, stream>>>(wbig, XhU, part, 256, 32768, 256, CSH, 65, 1, 15, 4, 1, 5);
    reduce_pad<<<1900, 256, 0, stream>>>(part, 256, 16, b_row_max, 256, c1rowb, CSV, 1, 53);

    // ---- conv2 col (horizontal 1x15), M=490 (Mpad 512): 15x * 4y(128) * 8z
    conv_tap<<<480, 256, 0, stream>>>(wc16, c1colb, part, 490, 4096, 512, CSH, 65, 1, 7, 3, 3, 5);
    reduce_bias<<<3637, 256, 0, stream>>>(part, 512, 8, b_col, 490, nullptr, 0, hcol);
    // ---- conv2 row (vertical 15x1); h = relu(hcol + this) ----
    conv_tap<<<480, 256, 0, stream>>>(wr16, c1rowb, part, 490, 4096, 512, CSV, 1, 53, 7, 3, 3, 5);
    reduce_bias<<<3637, 256, 0, stream>>>(part, 512, 8, b_row, 490, hcol, 1, h);

    // ---- PSROI pooling ----
    pool_kernel<<<512, 512, 0, stream>>>(h, rois, pooledb);

    float* out = (float*)d_out;
    // fc1: M=2048, K=512, split 2, relu -> bf16
    fc_mfma<<<dim3(32, 8, 2), 256, 0, stream>>>(wfc1b, pooledb, part, 2048, 512, 2048);
    fc_reduce<<<4096, 256, 0, stream>>>(part, 2048, 2048, 2, b_fc1, 1, nullptr, fc1b);
    // roi_cls_locs: M=324, K=2048, split 4
    fc_mfma<<<dim3(6, 8, 4), 256, 0, stream>>>(wlocb, fc1b, part, 324, 2048, 384);
    fc_reduce<<<648, 256, 0, stream>>>(part, 384, 324, 4, b_loc, 0, out, nullptr);
    // roi_scores: M=81, K=2048, split 8
    fc_mfma<<<dim3(2, 8, 8), 256, 0, stream>>>(wscoreb, fc1b, part, 81, 2048, 128);
    fc_reduce<<<162, 256, 0, stream>>>(part, 128, 81, 8, b_score, 0, out + 512 * 324, nullptr);
}

// Round 9
// 392.773 us; speedup vs baseline: 1.7144x; 1.0770x over previous
//
#include <hip/hip_runtime.h>
#include <math.h>

#define FW 50
#define FH 38
#define NPIX 1900   // 38*50
#define NROIS 512

// padded layouts
#define CSH 2470    // horizontal-consumed: [c][y*65 + x + t], width 65 = 50+15
#define CSV 2650    // vertical-consumed:   [c][x*53 + y + t], height 53 = 38+15

typedef __bf16 bf16x8 __attribute__((ext_vector_type(8)));
typedef float  f32x4  __attribute__((ext_vector_type(4)));
typedef float  f32x16 __attribute__((ext_vector_type(16)));

__device__ __forceinline__ unsigned short f2b(float f) {
    unsigned int u = __float_as_uint(f);
    unsigned int r = (u + 0x7fffu + ((u >> 16) & 1u)) >> 16;   // RNE
    return (unsigned short)r;
}

// ---------------- prep kernels ----------------

__global__ __launch_bounds__(256) void zero_us(unsigned short* __restrict__ p, int n) {
    int i = (blockIdx.x * 256 + threadIdx.x) * 8;
    if (i < n) { uint4 z; z.x = z.y = z.z = z.w = 0u; *(uint4*)(p + i) = z; }
}

__global__ __launch_bounds__(256) void cvt_bf16(
    const float* __restrict__ in, unsigned short* __restrict__ out, int n)
{
    int i = (blockIdx.x * 256 + threadIdx.x) * 4;
    if (i >= n) return;
    float4 v = *(const float4*)(in + i);
    ushort2 a, b;
    a.x = f2b(v.x); a.y = f2b(v.y);
    b.x = f2b(v.z); b.y = f2b(v.w);
    *(ushort2*)(out + i)     = a;
    *(ushort2*)(out + i + 2) = b;
}

__global__ __launch_bounds__(256) void cvt_pad(
    const float* __restrict__ in, unsigned short* __restrict__ out,
    int rows, int Kin, int Kout)
{
    int idx = blockIdx.x * 256 + threadIdx.x;
    if (idx >= rows * Kout) return;
    int rw = idx / Kout, k = idx - rw * Kout;
    out[idx] = (k < Kin) ? f2b(in[(size_t)rw * Kin + k]) : (unsigned short)0;
}

// weights fp32 [M][Kc][15] -> bf16 [M][Kc*16] (tap 15 = 0)
__global__ __launch_bounds__(256) void repack_w(
    const float* __restrict__ w, unsigned short* __restrict__ out, int n)
{
    int idx = blockIdx.x * 256 + threadIdx.x;
    if (idx >= n) return;
    int t = idx & 15;
    int oc = idx >> 4;
    out[idx] = (t < 15) ? f2b(w[oc * 15 + t]) : (unsigned short)0;
}

// x fp32 [c][y][x] -> bf16 padded horizontal [c][y*65 + xc], xc = x+7
__global__ __launch_bounds__(256) void xpad_h(
    const float* __restrict__ xs, unsigned short* __restrict__ out)
{
    int idx = blockIdx.x * 256 + threadIdx.x;
    if (idx >= 2048 * CSH) return;
    int c = idx / CSH;
    int rem = idx - c * CSH;
    int y = rem / 65;
    int xc = rem - y * 65 - 7;
    unsigned short v = 0;
    if (xc >= 0 && xc < FW) v = f2b(xs[(c * FH + y) * FW + xc]);
    out[idx] = v;
}

// x fp32 [c][y][x] -> bf16 padded vertical (x-major) [c][x*53 + yc], yc = y+7
__global__ __launch_bounds__(256) void xpad_v(
    const float* __restrict__ xs, unsigned short* __restrict__ out)
{
    int idx = blockIdx.x * 256 + threadIdx.x;
    if (idx >= 2048 * CSV) return;
    int c = idx / CSV;
    int rem = idx - c * CSV;
    int xx = rem / 53;
    int yc = rem - xx * 53 - 7;
    unsigned short v = 0;
    if (yc >= 0 && yc < FH) v = f2b(xs[(c * FH + yc) * FW + xx]);
    out[idx] = v;
}

// ---------------------------------------------------------------------------
// DUAL tap-padded bf16 conv-as-GEMM: col-path and row-path convs fused in one
// dispatch (independent inputs/outputs). Block picks path by blockIdx.x.
// Per path: block tile 128(M) x 128(pix), 4 waves 2x2 of 64x64 (32x32x16
// MFMA), BK=32, double-buffered LDS, one barrier per K-step.
// C/D layout (32x32): col=lane&31, row=(reg&3)+8*(reg>>2)+4*(lane>>5).
// ---------------------------------------------------------------------------
__global__ __launch_bounds__(256) void conv_dual(
    const unsigned short* __restrict__ W0, const unsigned short* __restrict__ X0,
    float* __restrict__ P0, int CS0, int yMul0, int xMul0,
    const unsigned short* __restrict__ W1, const unsigned short* __restrict__ X1,
    float* __restrict__ P1, int CS1, int yMul1, int xMul1,
    int M, int Kp, int Mpad,
    int zMask, int zBits, int yMask, int xShift, int halfGrid)
{
    int id = blockIdx.x;
    const unsigned short* Wt; const unsigned short* Xp; float* P;
    int CS, yMul, xMul;
    if (id < halfGrid) {
        Wt = W0; Xp = X0; P = P0; CS = CS0; yMul = yMul0; xMul = xMul0;
    } else {
        id -= halfGrid;
        Wt = W1; Xp = X1; P = P1; CS = CS1; yMul = yMul1; xMul = xMul1;
    }
    const int zt = id & zMask;
    const int yt = (id >> zBits) & yMask;
    const int xt = id >> xShift;
    const int nsplit = zMask + 1;

    const int Ks = Kp / nsplit;
    const int k0 = zt * Ks;
    const int tid  = threadIdx.x;
    const int lane = tid & 63;
    const int wave = tid >> 6;
    const int mbase = yt * 128;
    const int pbase = xt * 128;

    __shared__ unsigned short As[2][128][40];
    __shared__ unsigned short Bt[2][128][40];

    // A staging: 128 rows x 32 k; thread: row=tid>>1, k-half=(tid&1)*16
    const int a_row = tid >> 1;
    const int a_k16 = (tid & 1) << 4;
    const int a_src = min(mbase + a_row, M - 1);   // clamp; dups land in Mpad pad
    const unsigned short* Abase = Wt + (size_t)a_src * Kp + a_k16;

    // B staging: 128 pixels x 32 k; thread: pixel=tid>>1, channel-half=tid&1
    const int b_pix = tid >> 1;
    const int bh    = tid & 1;
    int p = pbase + b_pix;
    if (p > NPIX - 1) p = NPIX - 1;          // clamp (stores guarded)
    const int py = p / FW, px = p - py * FW;
    const int pixBase = py * yMul + px * xMul;
    const unsigned* __restrict__ Bdw = (const unsigned*)Xp;

    f32x16 acc[2][2];
#pragma unroll
    for (int i = 0; i < 2; ++i)
#pragma unroll
        for (int j = 0; j < 2; ++j)
#pragma unroll
            for (int r = 0; r < 16; ++r) acc[i][j][r] = 0.f;

    const int wy = (wave >> 1) * 64;
    const int wx = (wave & 1) * 64;
    const int l5 = lane & 31;
    const int l8 = (lane >> 5) * 8;

    uint4 aR0, aR1;
    unsigned d[9];

    auto loadA = [&](int kt) {
        aR0 = *(const uint4*)(Abase + kt);
        aR1 = *(const uint4*)(Abase + kt + 8);
    };
    auto loadB = [&](int kt) {
        const int cg = (kt >> 4) + bh;               // this thread's channel
        const unsigned base = ((unsigned)(cg * CS + pixBase)) >> 1;
#pragma unroll
        for (int j = 0; j < 9; ++j) d[j] = Bdw[base + j];
    };

    loadA(k0); loadB(k0);
    const unsigned sh = ((unsigned)(pixBase & 1)) << 4;  // CS even -> parity fixed

    int buf = 0;
    for (int kt = k0; kt < k0 + Ks; kt += 32) {
        unsigned ob[8];
#pragma unroll
        for (int j = 0; j < 8; ++j)
            ob[j] = __builtin_amdgcn_alignbit(d[j + 1], d[j], sh);
        *(uint4*)&As[buf][a_row][a_k16]     = aR0;
        *(uint4*)&As[buf][a_row][a_k16 + 8] = aR1;
        *(uint4*)&Bt[buf][b_pix][bh * 16]     = *(uint4*)&ob[0];
        *(uint4*)&Bt[buf][b_pix][bh * 16 + 8] = *(uint4*)&ob[4];
        __syncthreads();

        if (kt + 32 < k0 + Ks) { loadA(kt + 32); loadB(kt + 32); }

        bf16x8 af[2][2], bfr[2][2];
#pragma unroll
        for (int i = 0; i < 2; ++i)
#pragma unroll
            for (int kk = 0; kk < 2; ++kk) {
                af[i][kk]  = __builtin_bit_cast(bf16x8,
                    *(const uint4*)&As[buf][wy + i * 32 + l5][kk * 16 + l8]);
                bfr[i][kk] = __builtin_bit_cast(bf16x8,
                    *(const uint4*)&Bt[buf][wx + i * 32 + l5][kk * 16 + l8]);
            }
#pragma unroll
        for (int kk = 0; kk < 2; ++kk)
#pragma unroll
            for (int i = 0; i < 2; ++i)
#pragma unroll
                for (int j = 0; j < 2; ++j)
                    acc[i][j] = __builtin_amdgcn_mfma_f32_32x32x16_bf16(
                        af[i][kk], bfr[j][kk], acc[i][j], 0, 0, 0);
        buf ^= 1;
    }

    float* Pp = P + (size_t)zt * Mpad * NPIX;
#pragma unroll
    for (int i = 0; i < 2; ++i) {
        const int mb = mbase + wy + i * 32 + (lane >> 5) * 4;
#pragma unroll
        for (int j = 0; j < 2; ++j) {
            const int pp = pbase + wx + j * 32 + l5;
            if (pp < NPIX) {
#pragma unroll
                for (int r = 0; r < 16; ++r) {
                    const int m = mb + (r & 3) + 8 * (r >> 2);
                    Pp[(size_t)m * NPIX + pp] = acc[i][j][r];
                }
            }
        }
    }
}

// conv1 dual reduce: both paths' partials + bias -> bf16 padded layouts
__global__ void reduce_pad_dual(
    const float* __restrict__ P0, const float* __restrict__ bias0,
    unsigned short* __restrict__ out0, int CS0, int yM0, int xM0,
    const float* __restrict__ P1, const float* __restrict__ bias1,
    unsigned short* __restrict__ out1, int CS1, int yM1, int xM1,
    int Mpad, int nsplit, int M, int halfGrid)
{
    int b = blockIdx.x;
    const float* P; const float* bias; unsigned short* outb;
    int CS, yMul, xMul;
    if (b < halfGrid) { P = P0; bias = bias0; outb = out0; CS = CS0; yMul = yM0; xMul = xM0; }
    else { b -= halfGrid; P = P1; bias = bias1; outb = out1; CS = CS1; yMul = yM1; xMul = xM1; }
    int idx = b * 256 + threadIdx.x;
    if (idx >= M * NPIX) return;
    int o = idx / NPIX;
    int p = idx - o * NPIX;
    float s = bias[o];
    for (int sp = 0; sp < nsplit; ++sp)
        s += P[((size_t)sp * Mpad + o) * NPIX + p];
    int y = p / FW, x = p - y * FW;
    outb[(size_t)o * CS + y * yMul + x * xMul + 7] = f2b(s);
}

// conv2 dual reduce: h = relu(sum P0 + sum P1 + b_col + b_row), fp32 raster
__global__ void reduce_bias_dual(
    const float* __restrict__ P0, const float* __restrict__ P1,
    int Mpad, int nsplit,
    const float* __restrict__ bias0, const float* __restrict__ bias1,
    int M, float* __restrict__ outf)
{
    int idx = blockIdx.x * 256 + threadIdx.x;
    if (idx >= M * NPIX) return;
    int o = idx / NPIX;
    int p = idx - o * NPIX;
    float s = bias0[o] + bias1[o];
    for (int sp = 0; sp < nsplit; ++sp) {
        s += P0[((size_t)sp * Mpad + o) * NPIX + p];
        s += P1[((size_t)sp * Mpad + o) * NPIX + p];
    }
    s = fmaxf(s, 0.f);
    outf[idx] = s;
}

// ---------------------------------------------------------------------------
// PSROI bilinear pooling (fp32 h) -> bf16 pooled [512][512] zero-padded
// ---------------------------------------------------------------------------
__global__ __launch_bounds__(512) void pool_kernel(
    const float* __restrict__ h, const float* __restrict__ rois,
    unsigned short* __restrict__ pooledb)
{
    int n = blockIdx.x;
    int k = threadIdx.x;
    if (k >= 490) {
        pooledb[(size_t)n * 512 + k] = 0;
        return;
    }
    float x1 = rois[n * 4 + 0], y1 = rois[n * 4 + 1];
    float x2 = rois[n * 4 + 2], y2 = rois[n * 4 + 3];
    float xmin = x1 * (1.f / 16.f) / 50.f;
    float ymin = y1 * (1.f / 16.f) / 38.f;
    float xmax = x2 * (1.f / 16.f) / 50.f;
    float ymax = y2 * (1.f / 16.f) / 38.f;
    float step_x = (xmax - xmin) / 7.f;
    float step_y = (ymax - ymin) / 7.f;
    int bin = k / 10;
    int bi = bin / 7, bj = bin - bi * 7;
    const float* ch = h + (size_t)k * NPIX;
    float m = -INFINITY;
#pragma unroll
    for (int sy = 0; sy < 2; ++sy) {
        float yv = (ymin + (float)(bi + sy) * step_y) * 37.f;
        float y0 = floorf(yv);
        float fy = yv - y0;
        int yi0 = min(max((int)y0, 0), 37);
        int yi1 = min(max((int)y0 + 1, 0), 37);
#pragma unroll
        for (int sx = 0; sx < 2; ++sx) {
            float xv = (xmin + (float)(bj + sx) * step_x) * 49.f;
            float x0 = floorf(xv);
            float fx = xv - x0;
            int xi0 = min(max((int)x0, 0), 49);
            int xi1 = min(max((int)x0 + 1, 0), 49);
            float v00 = ch[yi0 * FW + xi0], v01 = ch[yi0 * FW + xi1];
            float v10 = ch[yi1 * FW + xi0], v11 = ch[yi1 * FW + xi1];
            float top = v00 + (v01 - v00) * fx;
            float bot = v10 + (v11 - v10) * fx;
            float val = top + (bot - top) * fy;
            m = fmaxf(m, val);
        }
    }
    pooledb[(size_t)n * 512 + k] = f2b(m);
}

// ---------------------------------------------------------------------------
// bf16 MFMA NT GEMM (FC): A = weights [M][Kld], B = acts [512][Kld], split-K.
// ---------------------------------------------------------------------------
__global__ __launch_bounds__(256) void fc_mfma(
    const unsigned short* __restrict__ Wb,
    const unsigned short* __restrict__ Act,
    float* __restrict__ P, int M, int Kld, int Mpad)
{
    const int Ks = Kld / gridDim.z;
    const int k0 = blockIdx.z * Ks;
    const int tid  = threadIdx.x;
    const int lane = tid & 63;
    const int wave = tid >> 6;
    const int mbase = blockIdx.x * 64;
    const int nbase = blockIdx.y * 64;

    __shared__ unsigned short As[64][40];
    __shared__ unsigned short Bs[64][40];

    const int s_r  = tid >> 2;
    const int s_k8 = (tid & 3) << 3;
    const int a_row = mbase + s_r;
    const bool a_ok = a_row < M;
    const unsigned short* Abase = Wb + (size_t)a_row * Kld + s_k8;
    const unsigned short* Bbase = Act + (size_t)(nbase + s_r) * Kld + s_k8;

    f32x4 acc[2][2];
#pragma unroll
    for (int i = 0; i < 2; ++i)
#pragma unroll
        for (int j = 0; j < 2; ++j)
#pragma unroll
            for (int r = 0; r < 4; ++r) acc[i][j][r] = 0.f;

    const int mh = (wave >> 1) * 32;
    const int nh = (wave & 1) * 32;
    const int lm = lane & 15;
    const int l8 = (lane >> 4) * 8;

    uint4 aReg, bReg;
    if (a_ok) aReg = *(const uint4*)(Abase + k0);
    else { aReg.x = aReg.y = aReg.z = aReg.w = 0u; }
    bReg = *(const uint4*)(Bbase + k0);

    for (int kt = k0; kt < k0 + Ks; kt += 32) {
        *(uint4*)&As[s_r][s_k8] = aReg;
        *(uint4*)&Bs[s_r][s_k8] = bReg;
        __syncthreads();

        if (kt + 32 < k0 + Ks) {
            if (a_ok) aReg = *(const uint4*)(Abase + kt + 32);
            bReg = *(const uint4*)(Bbase + kt + 32);
        }

        bf16x8 a0 = __builtin_bit_cast(bf16x8, *(const uint4*)&As[mh + lm][l8]);
        bf16x8 a1 = __builtin_bit_cast(bf16x8, *(const uint4*)&As[mh + 16 + lm][l8]);
        bf16x8 b0 = __builtin_bit_cast(bf16x8, *(const uint4*)&Bs[nh + lm][l8]);
        bf16x8 b1 = __builtin_bit_cast(bf16x8, *(const uint4*)&Bs[nh + 16 + lm][l8]);

        acc[0][0] = __builtin_amdgcn_mfma_f32_16x16x32_bf16(a0, b0, acc[0][0], 0, 0, 0);
        acc[0][1] = __builtin_amdgcn_mfma_f32_16x16x32_bf16(a0, b1, acc[0][1], 0, 0, 0);
        acc[1][0] = __builtin_amdgcn_mfma_f32_16x16x32_bf16(a1, b0, acc[1][0], 0, 0, 0);
        acc[1][1] = __builtin_amdgcn_mfma_f32_16x16x32_bf16(a1, b1, acc[1][1], 0, 0, 0);
        __syncthreads();
    }

#pragma unroll
    for (int ms = 0; ms < 2; ++ms)
#pragma unroll
        for (int ns = 0; ns < 2; ++ns) {
            int n  = nbase + nh + ns * 16 + lm;
            int m0 = mbase + mh + ms * 16 + (lane >> 4) * 4;
            float* Pp = P + ((size_t)blockIdx.z * NROIS + n) * Mpad + m0;
            *(f32x4*)Pp = acc[ms][ns];
        }
}

__global__ void fc_reduce(
    const float* __restrict__ P, int Mpad, int M, int nsplit,
    const float* __restrict__ bias, int relu,
    float* __restrict__ outf, unsigned short* __restrict__ outb)
{
    int idx = blockIdx.x * 256 + threadIdx.x;
    if (idx >= NROIS * M) return;
    int n = idx / M, m = idx - n * M;
    float s = bias[m];
    for (int sp = 0; sp < nsplit; ++sp)
        s += P[((size_t)sp * NROIS + n) * Mpad + m];
    if (relu) s = fmaxf(s, 0.f);
    if (outf) outf[idx] = s;
    if (outb) outb[idx] = f2b(s);
}

extern "C" void kernel_launch(void* const* d_in, const int* in_sizes, int n_in,
                              void* d_out, int out_size, void* d_ws, size_t ws_size,
                              hipStream_t stream) {
    const float* x         = (const float*)d_in[0];
    const float* rois      = (const float*)d_in[1];
    const float* w_col_max = (const float*)d_in[2];
    const float* b_col_max = (const float*)d_in[3];
    const float* w_col     = (const float*)d_in[4];
    const float* b_col     = (const float*)d_in[5];
    const float* w_row_max = (const float*)d_in[6];
    const float* b_row_max = (const float*)d_in[7];
    const float* w_row     = (const float*)d_in[8];
    const float* b_row     = (const float*)d_in[9];
    const float* w_fc1     = (const float*)d_in[10];
    const float* b_fc1     = (const float*)d_in[11];
    const float* w_score   = (const float*)d_in[12];
    const float* b_score   = (const float*)d_in[13];
    const float* w_loc     = (const float*)d_in[14];
    const float* b_loc     = (const float*)d_in[15];

    float* part0 = (float*)d_ws;                       // 7,782,400 f = 31.1 MB
    float* part1 = part0 + 7782400;                    // 7,782,400 f = 31.1 MB
    unsigned short* XvU   = (unsigned short*)(part1 + 7782400); // 5,427,264
    unsigned short* XhU   = XvU + 5427264;             // 5,058,624
    unsigned short* wbig0 = XhU + 5058624;             // 8,388,608 (col-max)
    unsigned short* wbig1 = wbig0 + 8388608;           // 8,388,608 (row-max)
    unsigned short* wc16  = wbig1 + 8388608;           // 2,007,040
    unsigned short* wr16  = wc16 + 2007040;            // 2,007,040
    unsigned short* c1colb= wr16 + 2007040;            //   632,384
    unsigned short* c1rowb= c1colb + 632384;           //   678,464
    unsigned short* wfc1b = c1rowb + 678464;           // 1,048,576
    unsigned short* pooledb = wfc1b + 1048576;         //   262,144
    unsigned short* fc1b  = pooledb + 262144;          // 1,048,576
    unsigned short* wlocb = fc1b + 1048576;            //   663,552
    unsigned short* wscoreb = wlocb + 663552;          //   165,888
    float* h = (float*)XhU;                            // alias (XhU dead after conv1)
    // total ~134 MB

    // ---- prep ----
    xpad_v<<<21200, 256, 0, stream>>>(x, XvU);
    xpad_h<<<19760, 256, 0, stream>>>(x, XhU);
    zero_us<<<641, 256, 0, stream>>>(c1colb, 1310848);   // c1colb + c1rowb (contiguous)
    repack_w<<<32768, 256, 0, stream>>>(w_col_max, wbig0, 8388608);
    repack_w<<<32768, 256, 0, stream>>>(w_row_max, wbig1, 8388608);
    repack_w<<<7840, 256, 0, stream>>>(w_col, wc16, 2007040);
    repack_w<<<7840, 256, 0, stream>>>(w_row, wr16, 2007040);
    cvt_pad <<<4096, 256, 0, stream>>>(w_fc1, wfc1b, 2048, 490, 512);
    cvt_bf16<<<648,  256, 0, stream>>>(w_loc, wlocb, 663552);
    cvt_bf16<<<162,  256, 0, stream>>>(w_score, wscoreb, 165888);

    // ---- conv1 col(vertical)+row(horizontal) fused: 2 x 480 blocks ----
    conv_dual<<<960, 256, 0, stream>>>(
        wbig0, XvU, part0, CSV, 1, 53,
        wbig1, XhU, part1, CSH, 65, 1,
        256, 32768, 256, 15, 4, 1, 5, 480);
    reduce_pad_dual<<<3800, 256, 0, stream>>>(
        part0, b_col_max, c1colb, CSH, 65, 1,
        part1, b_row_max, c1rowb, CSV, 1, 53,
        256, 16, 256, 1900);

    // ---- conv2 col(horizontal)+row(vertical) fused ----
    conv_dual<<<960, 256, 0, stream>>>(
        wc16, c1colb, part0, CSH, 65, 1,
        wr16, c1rowb, part1, CSV, 1, 53,
        490, 4096, 512, 7, 3, 3, 5, 480);
    reduce_bias_dual<<<3637, 256, 0, stream>>>(
        part0, part1, 512, 8, b_col, b_row, 490, h);

    // ---- PSROI pooling ----
    pool_kernel<<<512, 512, 0, stream>>>(h, rois, pooledb);

    float* out = (float*)d_out;
    // fc1: M=2048, K=512, split 2, relu -> bf16
    fc_mfma<<<dim3(32, 8, 2), 256, 0, stream>>>(wfc1b, pooledb, part0, 2048, 512, 2048);
    fc_reduce<<<4096, 256, 0, stream>>>(part0, 2048, 2048, 2, b_fc1, 1, nullptr, fc1b);
    // roi_cls_locs: M=324, K=2048, split 4
    fc_mfma<<<dim3(6, 8, 4), 256, 0, stream>>>(wlocb, fc1b, part0, 324, 2048, 384);
    fc_reduce<<<648, 256, 0, stream>>>(part0, 384, 324, 4, b_loc, 0, out, nullptr);
    // roi_scores: M=81, K=2048, split 8
    fc_mfma<<<dim3(2, 8, 8), 256, 0, stream>>>(wscoreb, fc1b, part0, 81, 2048, 128);
    fc_reduce<<<162, 256, 0, stream>>>(part0, 128, 81, 8, b_score, 0, out + 512 * 324, nullptr);
}